// Round 6
// baseline (1756.992 us; speedup 1.0000x reference)
//
#include <hip/hip_runtime.h>
#include <hip/hip_bf16.h>
#include <cmath>

typedef __hip_bfloat16 bf16;
typedef __attribute__((ext_vector_type(8))) __bf16 bf16x8;
typedef __attribute__((ext_vector_type(4))) float f32x4;

#define NROWS 50176   // 1024 windows * 49 tokens

static __device__ __forceinline__ float b2f(bf16 v) { return __bfloat162float(v); }
static __device__ __forceinline__ bf16 f2b(float v) { return __float2bfloat16(v); }

// map global window-row -> element base of pixel in x[16,56,56,512] after roll(-3,-3)
static __device__ __forceinline__ size_t pix_base(int row) {
  if (row >= NROWS) row = NROWS - 1;
  int win = row / 49, tok = row - win * 49;
  int b = win >> 6, wi = win & 63;
  int th = tok / 7, tw = tok - th * 7;
  int h = (wi >> 3) * 7 + th + 3; if (h >= 56) h -= 56;
  int w = (wi & 7) * 7 + tw + 3;  if (w >= 56) w -= 56;
  return (((size_t)b * 56 + h) * 56 + w) * 512;
}

// ---------------------------------------------------------------------------
__global__ __launch_bounds__(256) void diag_fill(float* out, float val, int n) {
  int i = blockIdx.x * 256 + threadIdx.x;
  if (i < n) out[i] = val;
}

// ---------------------------------------------------------------------------
// transpose f32 in[R][C] -> bf16 out[C][R]
__global__ __launch_bounds__(256) void transpose_f2b(const float* __restrict__ in,
                                                     bf16* __restrict__ out,
                                                     int R, int C) {
  __shared__ float tile[32][33];
  int c0 = blockIdx.x * 32, r0 = blockIdx.y * 32;
  int tx = threadIdx.x & 31, ty = threadIdx.x >> 5;
  for (int i = ty; i < 32; i += 8)
    tile[i][tx] = in[(size_t)(r0 + i) * C + c0 + tx];
  __syncthreads();
  for (int i = ty; i < 32; i += 8)
    out[(size_t)(c0 + i) * R + r0 + tx] = f2b(tile[tx][i]);
}

// ---------------------------------------------------------------------------
__global__ void prep_small(const float* qb, const float* vb, const float* pb,
                           const float* f1b, const float* f2b_, const float* ls,
                           float* qkvb, float* pbf, float* f1bf, float* f2bf,
                           float* scale) {
  int tid = blockIdx.x * 256 + threadIdx.x;   // 0..2047
  if (tid < 512)       qkvb[tid] = qb[tid];
  else if (tid < 1024) qkvb[tid] = 0.f;
  else if (tid < 1536) qkvb[tid] = vb[tid - 1024];
  if (tid < 512)  pbf[tid]  = pb[tid];
  if (tid < 2048) f1bf[tid] = f1b[tid];
  if (tid < 512)  f2bf[tid] = f2b_[tid];
  if (tid < 16)   scale[tid] = expf(fminf(ls[tid], 4.6051701859880914f));
}

__global__ __launch_bounds__(256) void prep_cpb(const float* __restrict__ coords,
                                                const float* __restrict__ w1,
                                                const float* __restrict__ b1,
                                                const float* __restrict__ w2,
                                                float* __restrict__ table) {
  __shared__ float hid[512];
  __shared__ float part[256];
  int idx = blockIdx.x;   // 0..168
  float c0 = coords[idx * 2], c1 = coords[idx * 2 + 1];
  int tid = threadIdx.x;
  for (int h = tid; h < 512; h += 256) {
    float v = c0 * w1[h] + c1 * w1[512 + h] + b1[h];
    hid[h] = fmaxf(v, 0.f);
  }
  __syncthreads();
  int head = tid & 15, seg = tid >> 4;
  float s = 0.f;
  for (int h = seg * 32; h < seg * 32 + 32; ++h) s += hid[h] * w2[h * 16 + head];
  part[tid] = s;
  __syncthreads();
  if (tid < 16) {
    float t = 0.f;
    for (int sg = 0; sg < 16; ++sg) t += part[sg * 16 + tid];
    table[idx * 16 + tid] = t;
  }
}

__global__ void prep_bias(const float* __restrict__ table, const int* __restrict__ rpi,
                          float* __restrict__ bias_full) {
  int idx = blockIdx.x * 256 + threadIdx.x;
  if (idx >= 16 * 2401) return;
  int head = idx / 2401, ij = idx - head * 2401;
  float t = table[rpi[ij] * 16 + head];
  bias_full[idx] = 16.f / (1.f + expf(-t));
}

// ---------------------------------------------------------------------------
// bf16 MFMA GEMM: C[.,N] = A[.,K](lda) * Bt[N,K]^T + bias, 128x128 tile
// EPI: 1=bias, 2=bias+gelu.  AF32: A is f32 (converted to bf16 during staging)
template <int EPI, int AF32>
__global__ __launch_bounds__(256, 2) void gemm_kernel(const void* Aq, int lda,
                                                      const bf16* __restrict__ Bt,
                                                      bf16* C, int ldc,
                                                      const float* __restrict__ bias,
                                                      int K) {
  constexpr int LP = 40;
  __shared__ __align__(16) bf16 As[128 * LP];
  __shared__ __align__(16) bf16 Bs[128 * LP];
  const int tid = threadIdx.x;
  const int lane = tid & 63;
  const int quad = lane >> 4;
  const int l15 = lane & 15;
  const int wave = tid >> 6;
  const int wm = (wave >> 1) * 64;
  const int wn = (wave & 1) * 64;
  const int row0 = blockIdx.y * 128;
  const int col0 = blockIdx.x * 128;
  const int r0 = tid >> 2, kc = (tid & 3) << 3;

  f32x4 acc[4][4] = {};

  for (int k0 = 0; k0 < K; k0 += 32) {
    if (AF32) {
      const float* A = (const float*)Aq;
#pragma unroll
      for (int half = 0; half < 2; ++half) {
        size_t off = (size_t)(row0 + r0 + half * 64) * lda + k0 + kc;
        float4 u0 = *(const float4*)&A[off];
        float4 u1 = *(const float4*)&A[off + 4];
        bf16 h8[8] = {f2b(u0.x), f2b(u0.y), f2b(u0.z), f2b(u0.w),
                      f2b(u1.x), f2b(u1.y), f2b(u1.z), f2b(u1.w)};
        *(uint4*)&As[(r0 + half * 64) * LP + kc] = *(uint4*)h8;
      }
    } else {
      const bf16* A = (const bf16*)Aq;
      *(uint4*)&As[r0 * LP + kc]        = *(const uint4*)&A[(size_t)(row0 + r0) * lda + k0 + kc];
      *(uint4*)&As[(r0 + 64) * LP + kc] = *(const uint4*)&A[(size_t)(row0 + r0 + 64) * lda + k0 + kc];
    }
    *(uint4*)&Bs[r0 * LP + kc]        = *(const uint4*)&Bt[(size_t)(col0 + r0) * K + k0 + kc];
    *(uint4*)&Bs[(r0 + 64) * LP + kc] = *(const uint4*)&Bt[(size_t)(col0 + r0 + 64) * K + k0 + kc];
    __syncthreads();
    bf16x8 af[4], bfr[4];
#pragma unroll
    for (int t = 0; t < 4; ++t) {
      af[t]  = *(const bf16x8*)&As[(wm + t * 16 + l15) * LP + quad * 8];
      bfr[t] = *(const bf16x8*)&Bs[(wn + t * 16 + l15) * LP + quad * 8];
    }
#pragma unroll
    for (int mt = 0; mt < 4; ++mt)
#pragma unroll
      for (int nt = 0; nt < 4; ++nt)
        acc[mt][nt] = __builtin_amdgcn_mfma_f32_16x16x32_bf16(af[mt], bfr[nt], acc[mt][nt], 0, 0, 0);
    __syncthreads();
  }

#pragma unroll
  for (int nt = 0; nt < 4; ++nt) {
    int gcol = col0 + wn + nt * 16 + l15;
    float bv = bias[gcol];
#pragma unroll
    for (int mt = 0; mt < 4; ++mt) {
      int grow = row0 + wm + mt * 16 + quad * 4;
#pragma unroll
      for (int r = 0; r < 4; ++r) {
        float v = acc[mt][nt][r] + bv;
        if (EPI == 2) v = 0.5f * v * (1.0f + erff(v * 0.70710678118654752f));
        C[(size_t)(grow + r) * ldc + gcol] = f2b(v);
      }
    }
  }
}

// qkv GEMM chunk; A = f32 x with fused roll+window gather, converted to bf16
__global__ __launch_bounds__(256, 2) void gemm_qkv(const float* __restrict__ X,
                                                   const bf16* __restrict__ Bt,
                                                   bf16* __restrict__ C,
                                                   const float* __restrict__ bias,
                                                   int row_off) {
  constexpr int LP = 40;
  constexpr int K = 512;
  __shared__ __align__(16) bf16 As[128 * LP];
  __shared__ __align__(16) bf16 Bs[128 * LP];
  const int tid = threadIdx.x;
  const int lane = tid & 63;
  const int quad = lane >> 4;
  const int l15 = lane & 15;
  const int wave = tid >> 6;
  const int wm = (wave >> 1) * 64;
  const int wn = (wave & 1) * 64;
  const int row0 = blockIdx.y * 128;
  const int col0 = blockIdx.x * 128;
  const int r0 = tid >> 2, kc = (tid & 3) << 3;
  const size_t base0 = pix_base(row_off + row0 + r0);
  const size_t base1 = pix_base(row_off + row0 + r0 + 64);

  f32x4 acc[4][4] = {};

  for (int k0 = 0; k0 < K; k0 += 32) {
    {
      float4 u0 = *(const float4*)&X[base0 + k0 + kc];
      float4 u1 = *(const float4*)&X[base0 + k0 + kc + 4];
      bf16 h8[8] = {f2b(u0.x), f2b(u0.y), f2b(u0.z), f2b(u0.w),
                    f2b(u1.x), f2b(u1.y), f2b(u1.z), f2b(u1.w)};
      *(uint4*)&As[r0 * LP + kc] = *(uint4*)h8;
      float4 v0 = *(const float4*)&X[base1 + k0 + kc];
      float4 v1 = *(const float4*)&X[base1 + k0 + kc + 4];
      bf16 g8[8] = {f2b(v0.x), f2b(v0.y), f2b(v0.z), f2b(v0.w),
                    f2b(v1.x), f2b(v1.y), f2b(v1.z), f2b(v1.w)};
      *(uint4*)&As[(r0 + 64) * LP + kc] = *(uint4*)g8;
    }
    *(uint4*)&Bs[r0 * LP + kc]        = *(const uint4*)&Bt[(size_t)(col0 + r0) * K + k0 + kc];
    *(uint4*)&Bs[(r0 + 64) * LP + kc] = *(const uint4*)&Bt[(size_t)(col0 + r0 + 64) * K + k0 + kc];
    __syncthreads();
    bf16x8 af[4], bfr[4];
#pragma unroll
    for (int t = 0; t < 4; ++t) {
      af[t]  = *(const bf16x8*)&As[(wm + t * 16 + l15) * LP + quad * 8];
      bfr[t] = *(const bf16x8*)&Bs[(wn + t * 16 + l15) * LP + quad * 8];
    }
#pragma unroll
    for (int mt = 0; mt < 4; ++mt)
#pragma unroll
      for (int nt = 0; nt < 4; ++nt)
        acc[mt][nt] = __builtin_amdgcn_mfma_f32_16x16x32_bf16(af[mt], bfr[nt], acc[mt][nt], 0, 0, 0);
    __syncthreads();
  }

#pragma unroll
  for (int nt = 0; nt < 4; ++nt) {
    int gcol = col0 + wn + nt * 16 + l15;
    float bv = bias[gcol];
#pragma unroll
    for (int mt = 0; mt < 4; ++mt) {
      int grow = row0 + wm + mt * 16 + quad * 4;
#pragma unroll
      for (int r = 0; r < 4; ++r)
        C[(size_t)(grow + r) * 1536 + gcol] = f2b(acc[mt][nt][r] + bv);
    }
  }
}

// ---------------------------------------------------------------------------
// fused cosine attention; one block per (local window, head); in-place q-slot
__global__ __launch_bounds__(256) void attn_kernel(const bf16* qkv,
                                                   const float* __restrict__ scale,
                                                   const float* __restrict__ bias_full,
                                                   const float* __restrict__ mask,
                                                   bf16* outp, int win_off) {
  __shared__ float sQ[49 * 32], sK[49 * 32], sV[49 * 32], sS[49 * 49];
  int head = blockIdx.x & 15;
  int winl = blockIdx.x >> 4;
  int wing = win_off + winl;
  int tid = threadIdx.x;
  size_t rowbase = (size_t)winl * 49;
  for (int idx = tid; idx < 49 * 32; idx += 256) {
    int t = idx >> 5, d = idx & 31;
    size_t r = (rowbase + t) * 1536 + head * 32 + d;
    sQ[idx] = b2f(qkv[r]);
    sK[idx] = b2f(qkv[r + 512]);
    sV[idx] = b2f(qkv[r + 1024]);
  }
  __syncthreads();
  float sc = scale[head];
  if (tid < 98) {
    int t = (tid < 49) ? tid : tid - 49;
    float* p = (tid < 49) ? sQ : sK;
    float s = 1e-20f;
    for (int d = 0; d < 32; ++d) { float v = p[t * 32 + d]; s += v * v; }
    float inv = rsqrtf(s);
    if (tid < 49) inv *= sc;
    for (int d = 0; d < 32; ++d) p[t * 32 + d] *= inv;
  }
  __syncthreads();
  const float* bh = bias_full + head * 2401;
  const float* mh = mask + (size_t)(wing & 63) * 2401;
  for (int idx = tid; idx < 2401; idx += 256) {
    int i = idx / 49, j = idx - i * 49;
    float s = 0.f;
    for (int d = 0; d < 32; ++d) s += sQ[i * 32 + d] * sK[j * 32 + d];
    sS[idx] = s + bh[idx] + mh[idx];
  }
  __syncthreads();
  if (tid < 49) {
    float m = -1e30f;
    for (int j = 0; j < 49; ++j) m = fmaxf(m, sS[tid * 49 + j]);
    float sum = 0.f;
    for (int j = 0; j < 49; ++j) { float e = expf(sS[tid * 49 + j] - m); sS[tid * 49 + j] = e; sum += e; }
    float inv = 1.f / sum;
    for (int j = 0; j < 49; ++j) sS[tid * 49 + j] *= inv;
  }
  __syncthreads();
  for (int idx = tid; idx < 49 * 32; idx += 256) {
    int i = idx >> 5, d = idx & 31;
    float s = 0.f;
    for (int j = 0; j < 49; ++j) s += sS[i * 49 + j] * sV[j * 32 + d];
    outp[(rowbase + i) * 1536 + head * 32 + d] = f2b(s);
  }
}

// ---------------------------------------------------------------------------
// per (win,tok) row: x1 = x + LN(proj), scattered to pixel row of f32 out
__global__ __launch_bounds__(256) void ln_shift_add(const bf16* projq,
                                                    const float* __restrict__ x,
                                                    const float* __restrict__ gamma,
                                                    const float* __restrict__ beta,
                                                    float* __restrict__ x1,
                                                    int row_off) {
  __shared__ float red[10];
  int grow = row_off + blockIdx.x;
  int win = grow / 49, tok = grow - win * 49;
  int b = win >> 6, wi = win & 63;
  int hs = (wi >> 3) * 7 + tok / 7;
  int wsc = (wi & 7) * 7 + tok % 7;
  int h = hs + 3; if (h >= 56) h -= 56;
  int w = wsc + 3; if (w >= 56) w -= 56;
  size_t pix = ((size_t)b * 56 + h) * 56 + w;
  const bf16* src = projq + (size_t)blockIdx.x * 1536 + 512;
  int tid = threadIdx.x;
  float a0 = b2f(src[tid]);
  float a1 = b2f(src[tid + 256]);
  float s = a0 + a1, q = a0 * a0 + a1 * a1;
#pragma unroll
  for (int off = 32; off > 0; off >>= 1) {
    s += __shfl_down(s, off, 64);
    q += __shfl_down(q, off, 64);
  }
  int lane = tid & 63, wv = tid >> 6;
  if (lane == 0) { red[wv] = s; red[4 + wv] = q; }
  __syncthreads();
  if (tid == 0) {
    red[8] = red[0] + red[1] + red[2] + red[3];
    red[9] = red[4] + red[5] + red[6] + red[7];
  }
  __syncthreads();
  float mu = red[8] * (1.f / 512.f);
  float inv = rsqrtf(fmaxf(red[9] * (1.f / 512.f) - mu * mu, 0.f) + 1e-5f);
  size_t base = pix * 512;
  float o0 = x[base + tid]       + (a0 - mu) * inv * gamma[tid]       + beta[tid];
  float o1 = x[base + tid + 256] + (a1 - mu) * inv * gamma[tid + 256] + beta[tid + 256];
  if (!__builtin_isfinite(o0)) o0 = 1000.f;   // phase-A garbage sentinel
  if (!__builtin_isfinite(o1)) o1 = 1000.f;
  x1[base + tid]       = o0;
  x1[base + tid + 256] = o1;
}

// out = x1 + LN(hsrc); x1/out alias (per-thread same-element RMW), f32
__global__ __launch_bounds__(256) void ln_add(const bf16* __restrict__ hsrc,
                                              float* x1,
                                              const float* __restrict__ gamma,
                                              const float* __restrict__ beta) {
  __shared__ float red[10];
  size_t base = (size_t)blockIdx.x * 512;
  int tid = threadIdx.x;
  float a0 = b2f(hsrc[base + tid]);
  float a1 = b2f(hsrc[base + tid + 256]);
  float s = a0 + a1, q = a0 * a0 + a1 * a1;
#pragma unroll
  for (int off = 32; off > 0; off >>= 1) {
    s += __shfl_down(s, off, 64);
    q += __shfl_down(q, off, 64);
  }
  int lane = tid & 63, wv = tid >> 6;
  if (lane == 0) { red[wv] = s; red[4 + wv] = q; }
  __syncthreads();
  if (tid == 0) {
    red[8] = red[0] + red[1] + red[2] + red[3];
    red[9] = red[4] + red[5] + red[6] + red[7];
  }
  __syncthreads();
  float mu = red[8] * (1.f / 512.f);
  float inv = rsqrtf(fmaxf(red[9] * (1.f / 512.f) - mu * mu, 0.f) + 1e-5f);
  float t0 = (a0 - mu) * inv * gamma[tid]       + beta[tid];
  float t1 = (a1 - mu) * inv * gamma[tid + 256] + beta[tid + 256];
  if (!__builtin_isfinite(t0)) t0 = 3000.f;   // phase-B garbage sentinel
  if (!__builtin_isfinite(t1)) t1 = 3000.f;
  x1[base + tid]       += t0;
  x1[base + tid + 256] += t1;
}

// ---------------------------------------------------------------------------
extern "C" void kernel_launch(void* const* d_in, const int* in_sizes, int n_in,
                              void* d_out, int out_size, void* d_ws, size_t ws_size,
                              hipStream_t stream) {
  const float* x       = (const float*)d_in[0];
  const float* qkv_w   = (const float*)d_in[1];
  const float* q_bias  = (const float*)d_in[2];
  const float* v_bias  = (const float*)d_in[3];
  const float* proj_w  = (const float*)d_in[4];
  const float* proj_b  = (const float*)d_in[5];
  const float* logit_s = (const float*)d_in[6];
  const float* cpb_w1  = (const float*)d_in[7];
  const float* cpb_b1  = (const float*)d_in[8];
  const float* cpb_w2  = (const float*)d_in[9];
  const float* rct     = (const float*)d_in[10];
  const float* gamma1  = (const float*)d_in[11];
  const float* beta1   = (const float*)d_in[12];
  const float* gamma2  = (const float*)d_in[13];
  const float* beta2   = (const float*)d_in[14];
  const float* fc1_w   = (const float*)d_in[15];
  const float* fc1_b   = (const float*)d_in[16];
  const float* fc2_w   = (const float*)d_in[17];
  const float* fc2_b   = (const float*)d_in[18];
  const int*   rpi     = (const int*)d_in[19];
  const float* amask   = (const float*)d_in[20];
  float* out = (float*)d_out;   // f32 output per reference dtype

  char* ws = (char*)d_ws;
  size_t cur = 0;
  auto alloc = [&](size_t bytes) { size_t o = cur; cur += (bytes + 255) & ~(size_t)255; return o; };
  size_t o_qkvb = alloc(1536 * 4);
  size_t o_pb   = alloc(512 * 4);
  size_t o_f1b  = alloc(2048 * 4);
  size_t o_f2b  = alloc(512 * 4);
  size_t o_scal = alloc(16 * 4);
  size_t o_tab  = alloc(169 * 16 * 4);
  size_t o_bias = alloc(16 * 2401 * 4);
  size_t o_wt1  = alloc((size_t)1536 * 512 * 2);
  size_t o_wt2  = alloc((size_t)512 * 512 * 2);
  size_t o_wt3  = alloc((size_t)2048 * 512 * 2);
  size_t o_wt4  = alloc((size_t)512 * 2048 * 2);
  size_t o_big  = cur;
  size_t avail  = (ws_size > o_big) ? ws_size - o_big : 0;

  // --- adaptive tier selection from actual ws_size ---
  const int wopts[] = {1024, 256, 128, 64, 32, 16, 8};
  int wA = 0, padA = 0;
  for (int i = 0; i < 7; ++i) {
    int rows = wopts[i] * 49;
    int pad = (rows + 127) & ~127;
    if ((size_t)pad * 1536 * 2 <= avail) { wA = wopts[i]; padA = pad; break; }
  }
  const int ropts[] = {6272, 3584, 1792, 896, 512, 256};
  int rB = 0;
  for (int i = 0; i < 6; ++i)
    if ((size_t)ropts[i] * 2560 * 2 <= avail) { rB = ropts[i]; break; }

  if (!wA || !rB) {
    float v = 20000.f + (float)(ws_size >> 20);
    diag_fill<<<(out_size + 255) / 256, 256, 0, stream>>>(out, v, out_size);
    return;
  }

  float* qkvb  = (float*)(ws + o_qkvb);
  float* pbf   = (float*)(ws + o_pb);
  float* f1bf  = (float*)(ws + o_f1b);
  float* f2bf  = (float*)(ws + o_f2b);
  float* scal  = (float*)(ws + o_scal);
  float* tab   = (float*)(ws + o_tab);
  float* biasF = (float*)(ws + o_bias);
  bf16* wt1 = (bf16*)(ws + o_wt1);
  bf16* wt2 = (bf16*)(ws + o_wt2);
  bf16* wt3 = (bf16*)(ws + o_wt3);
  bf16* wt4 = (bf16*)(ws + o_wt4);
  bf16* big = (bf16*)(ws + o_big);

  transpose_f2b<<<dim3(48, 16), 256, 0, stream>>>(qkv_w, wt1, 512, 1536);
  transpose_f2b<<<dim3(16, 16), 256, 0, stream>>>(proj_w, wt2, 512, 512);
  transpose_f2b<<<dim3(64, 16), 256, 0, stream>>>(fc1_w, wt3, 512, 2048);
  transpose_f2b<<<dim3(16, 64), 256, 0, stream>>>(fc2_w, wt4, 2048, 512);

  prep_small<<<8, 256, 0, stream>>>(q_bias, v_bias, proj_b, fc1_b, fc2_b, logit_s,
                                    qkvb, pbf, f1bf, f2bf, scal);
  prep_cpb<<<169, 256, 0, stream>>>(rct, cpb_w1, cpb_b1, cpb_w2, tab);
  prep_bias<<<151, 256, 0, stream>>>(tab, rpi, biasF);

  // Phase A: qkv -> attn -> proj -> x1 = x + LN(proj) scattered into f32 out
  for (int woff = 0; woff < 1024; woff += wA) {
    int row_off = woff * 49;
    int rows = wA * 49;
    bf16* qkvC = big;   // [padA,1536]
    gemm_qkv<<<dim3(12, padA / 128), 256, 0, stream>>>(x, wt1, qkvC, qkvb, row_off);
    attn_kernel<<<wA * 16, 256, 0, stream>>>(qkvC, scal, biasF, amask, qkvC, woff);
    gemm_kernel<1, 0><<<dim3(4, padA / 128), 256, 0, stream>>>(qkvC, 1536, wt2, qkvC + 512, 1536, pbf, 512);
    ln_shift_add<<<rows, 256, 0, stream>>>(qkvC, x, gamma1, beta1, out, row_off);
  }
  // Phase B: fc1 -> fc2 -> out += LN(h2)  (in-place on f32 out rows)
  for (int r0 = 0; r0 < NROWS; r0 += rB) {
    float* x1h = out + (size_t)r0 * 512;
    bf16* hC  = big;                        // [rB,2048]
    bf16* f2C = big + (size_t)rB * 2048;    // [rB,512]
    gemm_kernel<2, 1><<<dim3(16, rB / 128), 256, 0, stream>>>(x1h, 512, wt3, hC, 2048, f1bf, 512);
    gemm_kernel<1, 0><<<dim3(4, rB / 128), 256, 0, stream>>>(hC, 2048, wt4, f2C, 512, f2bf, 2048);
    ln_add<<<rB, 256, 0, stream>>>(f2C, x1h, gamma2, beta2);
  }
}

// Round 7
// 1380.635 us; speedup vs baseline: 1.2726x; 1.2726x over previous
//
#include <hip/hip_runtime.h>
#include <hip/hip_bf16.h>
#include <cmath>

typedef __hip_bfloat16 bf16;
typedef __attribute__((ext_vector_type(8))) __bf16 bf16x8;
typedef __attribute__((ext_vector_type(4))) float f32x4;

#define NROWS 50176   // 1024 windows * 49 tokens

static __device__ __forceinline__ float b2f(bf16 v) { return __bfloat162float(v); }
static __device__ __forceinline__ bf16 f2b(float v) { return __float2bfloat16(v); }

// map global window-row -> element base of pixel in x[16,56,56,512] after roll(-3,-3)
static __device__ __forceinline__ size_t pix_base(int row) {
  if (row >= NROWS) row = NROWS - 1;
  int win = row / 49, tok = row - win * 49;
  int b = win >> 6, wi = win & 63;
  int th = tok / 7, tw = tok - th * 7;
  int h = (wi >> 3) * 7 + th + 3; if (h >= 56) h -= 56;
  int w = (wi & 7) * 7 + tw + 3;  if (w >= 56) w -= 56;
  return (((size_t)b * 56 + h) * 56 + w) * 512;
}

// ---------------------------------------------------------------------------
__global__ __launch_bounds__(256) void diag_fill(float* out, float val, int n) {
  int i = blockIdx.x * 256 + threadIdx.x;
  if (i < n) out[i] = val;
}

// ---------------------------------------------------------------------------
// transpose f32 in[R][C] -> bf16 out[C][R]
__global__ __launch_bounds__(256) void transpose_f2b(const float* __restrict__ in,
                                                     bf16* __restrict__ out,
                                                     int R, int C) {
  __shared__ float tile[32][33];
  int c0 = blockIdx.x * 32, r0 = blockIdx.y * 32;
  int tx = threadIdx.x & 31, ty = threadIdx.x >> 5;
  for (int i = ty; i < 32; i += 8)
    tile[i][tx] = in[(size_t)(r0 + i) * C + c0 + tx];
  __syncthreads();
  for (int i = ty; i < 32; i += 8)
    out[(size_t)(c0 + i) * R + r0 + tx] = f2b(tile[tx][i]);
}

// ---------------------------------------------------------------------------
__global__ void prep_small(const float* qb, const float* vb, const float* pb,
                           const float* f1b, const float* f2b_, const float* ls,
                           float* qkvb, float* pbf, float* f1bf, float* f2bf,
                           float* scale) {
  int tid = blockIdx.x * 256 + threadIdx.x;   // 0..2047
  if (tid < 512)       qkvb[tid] = qb[tid];
  else if (tid < 1024) qkvb[tid] = 0.f;
  else if (tid < 1536) qkvb[tid] = vb[tid - 1024];
  if (tid < 512)  pbf[tid]  = pb[tid];
  if (tid < 2048) f1bf[tid] = f1b[tid];
  if (tid < 512)  f2bf[tid] = f2b_[tid];
  if (tid < 16)   scale[tid] = expf(fminf(ls[tid], 4.6051701859880914f));
}

__global__ __launch_bounds__(256) void prep_cpb(const float* __restrict__ coords,
                                                const float* __restrict__ w1,
                                                const float* __restrict__ b1,
                                                const float* __restrict__ w2,
                                                float* __restrict__ table) {
  __shared__ float hid[512];
  __shared__ float part[256];
  int idx = blockIdx.x;   // 0..168
  float c0 = coords[idx * 2], c1 = coords[idx * 2 + 1];
  int tid = threadIdx.x;
  for (int h = tid; h < 512; h += 256) {
    float v = c0 * w1[h] + c1 * w1[512 + h] + b1[h];
    hid[h] = fmaxf(v, 0.f);
  }
  __syncthreads();
  int head = tid & 15, seg = tid >> 4;
  float s = 0.f;
  for (int h = seg * 32; h < seg * 32 + 32; ++h) s += hid[h] * w2[h * 16 + head];
  part[tid] = s;
  __syncthreads();
  if (tid < 16) {
    float t = 0.f;
    for (int sg = 0; sg < 16; ++sg) t += part[sg * 16 + tid];
    table[idx * 16 + tid] = t;
  }
}

__global__ void prep_bias(const float* __restrict__ table, const int* __restrict__ rpi,
                          float* __restrict__ bias_full) {
  int idx = blockIdx.x * 256 + threadIdx.x;
  if (idx >= 16 * 2401) return;
  int head = idx / 2401, ij = idx - head * 2401;
  float t = table[rpi[ij] * 16 + head];
  bias_full[idx] = 16.f / (1.f + expf(-t));
}

// ---------------------------------------------------------------------------
// bf16 MFMA GEMM: C[.,N] = A[.,K](lda) * Bt[N,K]^T + bias, 128x128 tile
// EPI: 1=bias, 2=bias+gelu.  AF32: A is f32 (converted to bf16 during staging)
template <int EPI, int AF32>
__global__ __launch_bounds__(256, 2) void gemm_kernel(const void* Aq, int lda,
                                                      const bf16* __restrict__ Bt,
                                                      bf16* C, int ldc,
                                                      const float* __restrict__ bias,
                                                      int K) {
  constexpr int LP = 40;
  __shared__ __align__(16) bf16 As[128 * LP];
  __shared__ __align__(16) bf16 Bs[128 * LP];
  const int tid = threadIdx.x;
  const int lane = tid & 63;
  const int quad = lane >> 4;
  const int l15 = lane & 15;
  const int wave = tid >> 6;
  const int wm = (wave >> 1) * 64;
  const int wn = (wave & 1) * 64;
  const int row0 = blockIdx.y * 128;
  const int col0 = blockIdx.x * 128;
  const int r0 = tid >> 2, kc = (tid & 3) << 3;

  f32x4 acc[4][4] = {};

  for (int k0 = 0; k0 < K; k0 += 32) {
    if (AF32) {
      const float* A = (const float*)Aq;
#pragma unroll
      for (int half = 0; half < 2; ++half) {
        size_t off = (size_t)(row0 + r0 + half * 64) * lda + k0 + kc;
        float4 u0 = *(const float4*)&A[off];
        float4 u1 = *(const float4*)&A[off + 4];
        bf16 h8[8] = {f2b(u0.x), f2b(u0.y), f2b(u0.z), f2b(u0.w),
                      f2b(u1.x), f2b(u1.y), f2b(u1.z), f2b(u1.w)};
        *(uint4*)&As[(r0 + half * 64) * LP + kc] = *(uint4*)h8;
      }
    } else {
      const bf16* A = (const bf16*)Aq;
      *(uint4*)&As[r0 * LP + kc]        = *(const uint4*)&A[(size_t)(row0 + r0) * lda + k0 + kc];
      *(uint4*)&As[(r0 + 64) * LP + kc] = *(const uint4*)&A[(size_t)(row0 + r0 + 64) * lda + k0 + kc];
    }
    *(uint4*)&Bs[r0 * LP + kc]        = *(const uint4*)&Bt[(size_t)(col0 + r0) * K + k0 + kc];
    *(uint4*)&Bs[(r0 + 64) * LP + kc] = *(const uint4*)&Bt[(size_t)(col0 + r0 + 64) * K + k0 + kc];
    __syncthreads();
    bf16x8 af[4], bfr[4];
#pragma unroll
    for (int t = 0; t < 4; ++t) {
      af[t]  = *(const bf16x8*)&As[(wm + t * 16 + l15) * LP + quad * 8];
      bfr[t] = *(const bf16x8*)&Bs[(wn + t * 16 + l15) * LP + quad * 8];
    }
#pragma unroll
    for (int mt = 0; mt < 4; ++mt)
#pragma unroll
      for (int nt = 0; nt < 4; ++nt)
        acc[mt][nt] = __builtin_amdgcn_mfma_f32_16x16x32_bf16(af[mt], bfr[nt], acc[mt][nt], 0, 0, 0);
    __syncthreads();
  }

#pragma unroll
  for (int nt = 0; nt < 4; ++nt) {
    int gcol = col0 + wn + nt * 16 + l15;
    float bv = bias[gcol];
#pragma unroll
    for (int mt = 0; mt < 4; ++mt) {
      int grow = row0 + wm + mt * 16 + quad * 4;
#pragma unroll
      for (int r = 0; r < 4; ++r) {
        float v = acc[mt][nt][r] + bv;
        if (EPI == 2) v = 0.5f * v * (1.0f + erff(v * 0.70710678118654752f));
        C[(size_t)(grow + r) * ldc + gcol] = f2b(v);
      }
    }
  }
}

// qkv GEMM chunk; A = f32 x with fused roll+window gather, converted to bf16
__global__ __launch_bounds__(256, 2) void gemm_qkv(const float* __restrict__ X,
                                                   const bf16* __restrict__ Bt,
                                                   bf16* __restrict__ C,
                                                   const float* __restrict__ bias,
                                                   int row_off) {
  constexpr int LP = 40;
  constexpr int K = 512;
  __shared__ __align__(16) bf16 As[128 * LP];
  __shared__ __align__(16) bf16 Bs[128 * LP];
  const int tid = threadIdx.x;
  const int lane = tid & 63;
  const int quad = lane >> 4;
  const int l15 = lane & 15;
  const int wave = tid >> 6;
  const int wm = (wave >> 1) * 64;
  const int wn = (wave & 1) * 64;
  const int row0 = blockIdx.y * 128;
  const int col0 = blockIdx.x * 128;
  const int r0 = tid >> 2, kc = (tid & 3) << 3;
  const size_t base0 = pix_base(row_off + row0 + r0);
  const size_t base1 = pix_base(row_off + row0 + r0 + 64);

  f32x4 acc[4][4] = {};

  for (int k0 = 0; k0 < K; k0 += 32) {
    {
      float4 u0 = *(const float4*)&X[base0 + k0 + kc];
      float4 u1 = *(const float4*)&X[base0 + k0 + kc + 4];
      bf16 h8[8] = {f2b(u0.x), f2b(u0.y), f2b(u0.z), f2b(u0.w),
                    f2b(u1.x), f2b(u1.y), f2b(u1.z), f2b(u1.w)};
      *(uint4*)&As[r0 * LP + kc] = *(uint4*)h8;
      float4 v0 = *(const float4*)&X[base1 + k0 + kc];
      float4 v1 = *(const float4*)&X[base1 + k0 + kc + 4];
      bf16 g8[8] = {f2b(v0.x), f2b(v0.y), f2b(v0.z), f2b(v0.w),
                    f2b(v1.x), f2b(v1.y), f2b(v1.z), f2b(v1.w)};
      *(uint4*)&As[(r0 + 64) * LP + kc] = *(uint4*)g8;
    }
    *(uint4*)&Bs[r0 * LP + kc]        = *(const uint4*)&Bt[(size_t)(col0 + r0) * K + k0 + kc];
    *(uint4*)&Bs[(r0 + 64) * LP + kc] = *(const uint4*)&Bt[(size_t)(col0 + r0 + 64) * K + k0 + kc];
    __syncthreads();
    bf16x8 af[4], bfr[4];
#pragma unroll
    for (int t = 0; t < 4; ++t) {
      af[t]  = *(const bf16x8*)&As[(wm + t * 16 + l15) * LP + quad * 8];
      bfr[t] = *(const bf16x8*)&Bs[(wn + t * 16 + l15) * LP + quad * 8];
    }
#pragma unroll
    for (int mt = 0; mt < 4; ++mt)
#pragma unroll
      for (int nt = 0; nt < 4; ++nt)
        acc[mt][nt] = __builtin_amdgcn_mfma_f32_16x16x32_bf16(af[mt], bfr[nt], acc[mt][nt], 0, 0, 0);
    __syncthreads();
  }

#pragma unroll
  for (int nt = 0; nt < 4; ++nt) {
    int gcol = col0 + wn + nt * 16 + l15;
    float bv = bias[gcol];
#pragma unroll
    for (int mt = 0; mt < 4; ++mt) {
      int grow = row0 + wm + mt * 16 + quad * 4;
#pragma unroll
      for (int r = 0; r < 4; ++r)
        C[(size_t)(grow + r) * 1536 + gcol] = f2b(acc[mt][nt][r] + bv);
    }
  }
}

// ---------------------------------------------------------------------------
// fused cosine attention; one block per (local window, head); in-place q-slot
// K stored transposed in LDS (leading dim 57) -> conflict-free QK^T reads.
__global__ __launch_bounds__(256) void attn_kernel(const bf16* qkv,
                                                   const float* __restrict__ scale,
                                                   const float* __restrict__ bias_full,
                                                   const float* __restrict__ mask,
                                                   bf16* outp, int win_off) {
  __shared__ float sQ[49 * 32];     // [i][d]
  __shared__ float sKT[32 * 57];    // [d][j], pad 57 (25d+j hits all banks)
  __shared__ float sV[49 * 32];     // [j][d]
  __shared__ float sS[2401];        // [i][j]
  int head = blockIdx.x & 15;
  int winl = blockIdx.x >> 4;
  int wing = win_off + winl;
  int tid = threadIdx.x;
  size_t rowbase = (size_t)winl * 49;
  for (int idx = tid; idx < 49 * 32; idx += 256) {
    int t = idx >> 5, d = idx & 31;
    size_t r = (rowbase + t) * 1536 + head * 32 + d;
    sQ[idx] = b2f(qkv[r]);
    sKT[d * 57 + t] = b2f(qkv[r + 512]);
    sV[idx] = b2f(qkv[r + 1024]);
  }
  __syncthreads();
  float sc = scale[head];
  if (tid < 98) {
    int t = (tid < 49) ? tid : tid - 49;
    if (tid < 49) {   // normalize Q row t (contiguous)
      float s = 1e-20f;
      for (int d = 0; d < 32; ++d) { float v = sQ[t * 32 + d]; s += v * v; }
      float inv = rsqrtf(s) * sc;
      for (int d = 0; d < 32; ++d) sQ[t * 32 + d] *= inv;
    } else {          // normalize K column t (stride 57 - conflict-free across lanes)
      float s = 1e-20f;
      for (int d = 0; d < 32; ++d) { float v = sKT[d * 57 + t]; s += v * v; }
      float inv = rsqrtf(s);
      for (int d = 0; d < 32; ++d) sKT[d * 57 + t] *= inv;
    }
  }
  __syncthreads();
  const float* bh = bias_full + head * 2401;
  const float* mh = mask + (size_t)(wing & 63) * 2401;
  for (int idx = tid; idx < 2401; idx += 256) {
    int i = idx / 49, j = idx - i * 49;
    float s = 0.f;
#pragma unroll 8
    for (int d = 0; d < 32; ++d) s += sQ[i * 32 + d] * sKT[d * 57 + j];
    sS[idx] = s + bh[idx] + mh[idx];
  }
  __syncthreads();
  if (tid < 49) {
    float m = -1e30f;
    for (int j = 0; j < 49; ++j) m = fmaxf(m, sS[tid * 49 + j]);
    float sum = 0.f;
    for (int j = 0; j < 49; ++j) { float e = expf(sS[tid * 49 + j] - m); sS[tid * 49 + j] = e; sum += e; }
    float inv = 1.f / sum;
    for (int j = 0; j < 49; ++j) sS[tid * 49 + j] *= inv;
  }
  __syncthreads();
  for (int idx = tid; idx < 49 * 32; idx += 256) {
    int i = idx >> 5, d = idx & 31;
    float s = 0.f;
#pragma unroll 7
    for (int j = 0; j < 49; ++j) s += sS[i * 49 + j] * sV[j * 32 + d];
    outp[(rowbase + i) * 1536 + head * 32 + d] = f2b(s);
  }
}

// ---------------------------------------------------------------------------
// per (win,tok) row: x1 = x + LN(proj), scattered to pixel row of f32 out
__global__ __launch_bounds__(256) void ln_shift_add(const bf16* projq,
                                                    const float* __restrict__ x,
                                                    const float* __restrict__ gamma,
                                                    const float* __restrict__ beta,
                                                    float* __restrict__ x1,
                                                    int row_off) {
  __shared__ float red[10];
  int grow = row_off + blockIdx.x;
  int win = grow / 49, tok = grow - win * 49;
  int b = win >> 6, wi = win & 63;
  int hs = (wi >> 3) * 7 + tok / 7;
  int wsc = (wi & 7) * 7 + tok % 7;
  int h = hs + 3; if (h >= 56) h -= 56;
  int w = wsc + 3; if (w >= 56) w -= 56;
  size_t pix = ((size_t)b * 56 + h) * 56 + w;
  const bf16* src = projq + (size_t)blockIdx.x * 1536 + 512;
  int tid = threadIdx.x;
  float a0 = b2f(src[tid]);
  float a1 = b2f(src[tid + 256]);
  float s = a0 + a1, q = a0 * a0 + a1 * a1;
#pragma unroll
  for (int off = 32; off > 0; off >>= 1) {
    s += __shfl_down(s, off, 64);
    q += __shfl_down(q, off, 64);
  }
  int lane = tid & 63, wv = tid >> 6;
  if (lane == 0) { red[wv] = s; red[4 + wv] = q; }
  __syncthreads();
  if (tid == 0) {
    red[8] = red[0] + red[1] + red[2] + red[3];
    red[9] = red[4] + red[5] + red[6] + red[7];
  }
  __syncthreads();
  float mu = red[8] * (1.f / 512.f);
  float inv = rsqrtf(fmaxf(red[9] * (1.f / 512.f) - mu * mu, 0.f) + 1e-5f);
  size_t base = pix * 512;
  x1[base + tid]       = x[base + tid]       + (a0 - mu) * inv * gamma[tid]       + beta[tid];
  x1[base + tid + 256] = x[base + tid + 256] + (a1 - mu) * inv * gamma[tid + 256] + beta[tid + 256];
}

// out = x1 + LN(hsrc); x1/out alias (per-thread same-element RMW), f32
__global__ __launch_bounds__(256) void ln_add(const bf16* __restrict__ hsrc,
                                              float* x1,
                                              const float* __restrict__ gamma,
                                              const float* __restrict__ beta) {
  __shared__ float red[10];
  size_t base = (size_t)blockIdx.x * 512;
  int tid = threadIdx.x;
  float a0 = b2f(hsrc[base + tid]);
  float a1 = b2f(hsrc[base + tid + 256]);
  float s = a0 + a1, q = a0 * a0 + a1 * a1;
#pragma unroll
  for (int off = 32; off > 0; off >>= 1) {
    s += __shfl_down(s, off, 64);
    q += __shfl_down(q, off, 64);
  }
  int lane = tid & 63, wv = tid >> 6;
  if (lane == 0) { red[wv] = s; red[4 + wv] = q; }
  __syncthreads();
  if (tid == 0) {
    red[8] = red[0] + red[1] + red[2] + red[3];
    red[9] = red[4] + red[5] + red[6] + red[7];
  }
  __syncthreads();
  float mu = red[8] * (1.f / 512.f);
  float inv = rsqrtf(fmaxf(red[9] * (1.f / 512.f) - mu * mu, 0.f) + 1e-5f);
  x1[base + tid]       += (a0 - mu) * inv * gamma[tid]       + beta[tid];
  x1[base + tid + 256] += (a1 - mu) * inv * gamma[tid + 256] + beta[tid + 256];
}

// ---------------------------------------------------------------------------
extern "C" void kernel_launch(void* const* d_in, const int* in_sizes, int n_in,
                              void* d_out, int out_size, void* d_ws, size_t ws_size,
                              hipStream_t stream) {
  const float* x       = (const float*)d_in[0];
  const float* qkv_w   = (const float*)d_in[1];
  const float* q_bias  = (const float*)d_in[2];
  const float* v_bias  = (const float*)d_in[3];
  const float* proj_w  = (const float*)d_in[4];
  const float* proj_b  = (const float*)d_in[5];
  const float* logit_s = (const float*)d_in[6];
  const float* cpb_w1  = (const float*)d_in[7];
  const float* cpb_b1  = (const float*)d_in[8];
  const float* cpb_w2  = (const float*)d_in[9];
  const float* rct     = (const float*)d_in[10];
  const float* gamma1  = (const float*)d_in[11];
  const float* beta1   = (const float*)d_in[12];
  const float* gamma2  = (const float*)d_in[13];
  const float* beta2   = (const float*)d_in[14];
  const float* fc1_w   = (const float*)d_in[15];
  const float* fc1_b   = (const float*)d_in[16];
  const float* fc2_w   = (const float*)d_in[17];
  const float* fc2_b   = (const float*)d_in[18];
  const int*   rpi     = (const int*)d_in[19];
  const float* amask   = (const float*)d_in[20];
  float* out = (float*)d_out;   // f32 output per reference dtype

  char* ws = (char*)d_ws;
  size_t cur = 0;
  auto alloc = [&](size_t bytes) { size_t o = cur; cur += (bytes + 255) & ~(size_t)255; return o; };
  size_t o_qkvb = alloc(1536 * 4);
  size_t o_pb   = alloc(512 * 4);
  size_t o_f1b  = alloc(2048 * 4);
  size_t o_f2b  = alloc(512 * 4);
  size_t o_scal = alloc(16 * 4);
  size_t o_tab  = alloc(169 * 16 * 4);
  size_t o_bias = alloc(16 * 2401 * 4);
  size_t o_wt1  = alloc((size_t)1536 * 512 * 2);
  size_t o_wt2  = alloc((size_t)512 * 512 * 2);
  size_t o_wt3  = alloc((size_t)2048 * 512 * 2);
  size_t o_wt4  = alloc((size_t)512 * 2048 * 2);
  size_t o_big  = cur;
  size_t avail  = (ws_size > o_big) ? ws_size - o_big : 0;

  // --- adaptive tier selection from actual ws_size ---
  const int wopts[] = {1024, 256, 128, 64, 32, 16, 8};
  int wA = 0, padA = 0;
  for (int i = 0; i < 7; ++i) {
    int rows = wopts[i] * 49;
    int pad = (rows + 127) & ~127;
    if ((size_t)pad * 1536 * 2 <= avail) { wA = wopts[i]; padA = pad; break; }
  }
  const int ropts[] = {25088, 12544, 6272, 3584, 1792, 896, 512, 256};
  int rB = 0;
  for (int i = 0; i < 8; ++i)
    if ((size_t)ropts[i] * 2560 * 2 <= avail) { rB = ropts[i]; break; }

  if (!wA || !rB) {
    float v = 20000.f + (float)(ws_size >> 20);
    diag_fill<<<(out_size + 255) / 256, 256, 0, stream>>>(out, v, out_size);
    return;
  }

  float* qkvb  = (float*)(ws + o_qkvb);
  float* pbf   = (float*)(ws + o_pb);
  float* f1bf  = (float*)(ws + o_f1b);
  float* f2bf  = (float*)(ws + o_f2b);
  float* scal  = (float*)(ws + o_scal);
  float* tab   = (float*)(ws + o_tab);
  float* biasF = (float*)(ws + o_bias);
  bf16* wt1 = (bf16*)(ws + o_wt1);
  bf16* wt2 = (bf16*)(ws + o_wt2);
  bf16* wt3 = (bf16*)(ws + o_wt3);
  bf16* wt4 = (bf16*)(ws + o_wt4);
  bf16* big = (bf16*)(ws + o_big);

  transpose_f2b<<<dim3(48, 16), 256, 0, stream>>>(qkv_w, wt1, 512, 1536);
  transpose_f2b<<<dim3(16, 16), 256, 0, stream>>>(proj_w, wt2, 512, 512);
  transpose_f2b<<<dim3(64, 16), 256, 0, stream>>>(fc1_w, wt3, 512, 2048);
  transpose_f2b<<<dim3(16, 64), 256, 0, stream>>>(fc2_w, wt4, 2048, 512);

  prep_small<<<8, 256, 0, stream>>>(q_bias, v_bias, proj_b, fc1_b, fc2_b, logit_s,
                                    qkvb, pbf, f1bf, f2bf, scal);
  prep_cpb<<<169, 256, 0, stream>>>(rct, cpb_w1, cpb_b1, cpb_w2, tab);
  prep_bias<<<151, 256, 0, stream>>>(tab, rpi, biasF);

  // Phase A: qkv -> attn -> proj -> x1 = x + LN(proj) scattered into f32 out
  for (int woff = 0; woff < 1024; woff += wA) {
    int row_off = woff * 49;
    int rows = wA * 49;
    bf16* qkvC = big;   // [padA,1536]
    gemm_qkv<<<dim3(12, padA / 128), 256, 0, stream>>>(x, wt1, qkvC, qkvb, row_off);
    attn_kernel<<<wA * 16, 256, 0, stream>>>(qkvC, scal, biasF, amask, qkvC, woff);
    gemm_kernel<1, 0><<<dim3(4, padA / 128), 256, 0, stream>>>(qkvC, 1536, wt2, qkvC + 512, 1536, pbf, 512);
    ln_shift_add<<<rows, 256, 0, stream>>>(qkvC, x, gamma1, beta1, out, row_off);
  }
  // Phase B: fc1 -> fc2 -> out += LN(h2)  (in-place on f32 out rows)
  for (int r0 = 0; r0 < NROWS; r0 += rB) {
    float* x1h = out + (size_t)r0 * 512;
    bf16* hC  = big;                        // [rB,2048]
    bf16* f2C = big + (size_t)rB * 2048;    // [rB,512]
    gemm_kernel<2, 1><<<dim3(16, rB / 128), 256, 0, stream>>>(x1h, 512, wt3, hC, 2048, f1bf, 512);
    gemm_kernel<1, 0><<<dim3(4, rB / 128), 256, 0, stream>>>(hC, 2048, wt4, f2C, 512, f2bf, 2048);
    ln_add<<<rB, 256, 0, stream>>>(f2C, x1h, gamma2, beta2);
  }
}